// Round 4
// baseline (11.330 us; speedup 1.0000x reference)
//
#include <hip/hip_runtime.h>

#define KK 17
#define MM 30
#define BB 8
#define HWN 262144

// One block, 256 threads. Threads [32b, 32b+31] handle batch b.
// Lane (tid&31) < 30 owns person m = lane: 17 branch-free int2 kp loads,
// then 17 branch-free unconditional tag gathers (mask applied as f32 mul).
// Push uses validity-encoded means (invalid -> (lane+1)*1e28 so any pair
// with an invalid person underflows exp to exact 0) and sums only the 465
// unordered pairs i<=j; every diagonal contributes exp(0)=1 regardless of
// validity, so full push = 2*(S - 30) + n. Single __syncthreads for the
// final cross-batch reduction. Deterministic, no atomics.
__global__ __launch_bounds__(256) void ae_loss_kernel(
    const float* __restrict__ tags,       // (B, K, HW) f32
    const int*   __restrict__ kp,         // (B, M, K, 2) i32: [idx, vis]
    float*       __restrict__ out)        // out[0]=pull_total, out[1]=push_total
{
    const int tid  = threadIdx.x;
    const int b    = tid >> 5;   // 0..7
    const int lane = tid & 31;   // 0..31

    __shared__ float s_res[BB][2];   // [pull_loss, push_loss] per batch

    float mean    = 0.0f;
    float pull_pp = 0.0f;
    int   valid   = 0;

    if (lane < MM) {
        const int m = lane;
        const int2* __restrict__ kp2 =
            (const int2*)(kp + (size_t)(b * MM + m) * KK * 2);

        int   idxv[KK];
        float msk[KK];
        int   cnt = 0;
        #pragma unroll
        for (int k = 0; k < KK; ++k) {
            const int2 p = kp2[k];          // 17 independent 8-B loads
            idxv[k] = p.x;
            const int v = (p.y > 0) ? 1 : 0;
            msk[k]  = (float)v;
            cnt    += v;
        }

        // Unconditional gathers (reference gathers regardless of vis).
        float g[KK];
        #pragma unroll
        for (int k = 0; k < KK; ++k)
            g[k] = tags[(size_t)(b * KK + k) * HWN + idxv[k]];

        float sum = 0.0f;
        #pragma unroll
        for (int k = 0; k < KK; ++k)
            sum += g[k] * msk[k];

        const float safe_cnt = (float)(cnt > 1 ? cnt : 1);
        mean = sum / safe_cnt;

        float pp = 0.0f;
        #pragma unroll
        for (int k = 0; k < KK; ++k) {
            const float d = g[k] - mean;
            pp += msk[k] * d * d;
        }
        pp /= safe_cnt;

        valid   = (cnt > 0) ? 1 : 0;
        pull_pp = valid ? pp : 0.0f;
    }

    // n = number of valid persons in this 32-lane group, via wave ballot.
    const unsigned long long bal = __ballot(valid != 0);
    const int n = __popcll((bal >> (tid & 32)) & 0xffffffffull);

    // Validity-encoded mean: invalid persons (and lanes 30/31, unused) get a
    // huge lane-distinct value so cross-validity diffs overflow -> exp == 0.
    const float mean_enc = valid ? mean : (float)(lane + 1) * 1e28f;

    // --- pull: reduce across the 32-lane group ---
    float pull = pull_pp;
    #pragma unroll
    for (int off = 16; off >= 1; off >>= 1)
        pull += __shfl_xor(pull, off);

    // --- push: 465 unordered pairs (i<=j), i,j < 30, across 32 lanes ---
    float S = 0.0f;
    for (int p = lane; p < (MM * (MM + 1)) / 2; p += 32) {
        // decode p -> (j <= i): tri(i) <= p < tri(i+1), j = p - tri(i)
        int i = (int)((__fsqrt_rn(8.0f * (float)p + 1.0f) - 1.0f) * 0.5f);
        while ((i + 1) * (i + 2) / 2 <= p) ++i;   // exact fixup (<=1 iter)
        while (i * (i + 1) / 2 > p) --i;
        const int j = p - i * (i + 1) / 2;
        const float mu1 = __shfl(mean_enc, i, 32);
        const float mu2 = __shfl(mean_enc, j, 32);
        const float d = mu1 - mu2;
        S += __expf(-d * d);
    }
    #pragma unroll
    for (int off = 16; off >= 1; off >>= 1)
        S += __shfl_xor(S, off);

    // full 30x30 masked sum = 2 * (S - 30 diag ones) + n valid diag ones
    const float push = 2.0f * (S - 30.0f) + (float)n;

    // --- per-batch finalize on lane 0 of each group ---
    if (lane == 0) {
        const float nf = (float)n;
        float push_loss = 0.0f;
        if (n > 1) {
            float denom = nf * (nf - 1.0f);
            if (denom < 1.0f) denom = 1.0f;
            push_loss = push / denom * 0.5f;
        }
        float pull_loss = 0.0f;
        if (n > 0) {
            float denom = nf > 1.0f ? nf : 1.0f;
            pull_loss = pull / denom;
        }
        s_res[b][0] = pull_loss;
        s_res[b][1] = push_loss;
    }
    __syncthreads();

    if (tid < 2) {
        float total = 0.0f;
        #pragma unroll
        for (int bb = 0; bb < BB; ++bb)
            total += s_res[bb][tid];
        out[tid] = total;   // out[0]=pull.sum(), out[1]=push.sum()
    }
}

extern "C" void kernel_launch(void* const* d_in, const int* in_sizes, int n_in,
                              void* d_out, int out_size, void* d_ws, size_t ws_size,
                              hipStream_t stream) {
    const float* tags = (const float*)d_in[0];
    const int*   kp   = (const int*)d_in[1];
    float*       out  = (float*)d_out;
    ae_loss_kernel<<<dim3(1), dim3(256), 0, stream>>>(tags, kp, out);
}